// Round 1
// baseline (408.662 us; speedup 1.0000x reference)
//
#include <hip/hip_runtime.h>
#include <hip/hip_bf16.h>
#include <cstdint>
#include <cstddef>

typedef __attribute__((ext_vector_type(8))) __bf16 bf16x8;
typedef __attribute__((ext_vector_type(4))) float f32x4;

#define LOG2E 1.4426950408889634f

__device__ __forceinline__ ushort f2b(float x) {
    union { float f; uint32_t u; } v; v.f = x;
    uint32_t r = v.u + 0x7FFFu + ((v.u >> 16) & 1u);   // RNE
    return (ushort)(r >> 16);
}

__device__ __forceinline__ void glds16(const void* g, void* l) {
    __builtin_amdgcn_global_load_lds(
        (const __attribute__((address_space(1))) void*)g,
        (__attribute__((address_space(3))) void*)l, 16, 0, 0);
}

// ---------------- convert f32 -> bf16, 8 elems/thread ----------------
__global__ __launch_bounds__(256) void k_convert(const float* __restrict__ in,
                                                 ushort* __restrict__ out, int n8) {
    int i = blockIdx.x * 256 + threadIdx.x;
    if (i >= n8) return;
    const float4* p = (const float4*)in + (size_t)i * 2;
    float4 a = p[0], b = p[1];
    ushort o[8] = { f2b(a.x), f2b(a.y), f2b(a.z), f2b(a.w),
                    f2b(b.x), f2b(b.y), f2b(b.z), f2b(b.w) };
    *(uint4*)(out + (size_t)i * 8) = *(const uint4*)o;
}

// ------------- transpose-convert: in f32 [R][C] -> out bf16 [C][R] -------------
__global__ __launch_bounds__(256) void k_transpose_w(const float* __restrict__ in,
                                                     ushort* __restrict__ out,
                                                     int R, int C) {
    __shared__ float tile[32][33];
    int c0 = blockIdx.x * 32, r0 = blockIdx.y * 32;
    int tx = threadIdx.x, ty = threadIdx.y;   // (32,8)
#pragma unroll
    for (int i = 0; i < 32; i += 8)
        tile[ty + i][tx] = in[(size_t)(r0 + ty + i) * C + c0 + tx];
    __syncthreads();
#pragma unroll
    for (int i = 0; i < 32; i += 8)
        out[(size_t)(c0 + ty + i) * R + r0 + tx] = f2b(tile[tx][ty + i]);
}

// ------------- transpose V [bh][T][D] bf16 -> VT [bh][D][T] bf16 -------------
__global__ __launch_bounds__(256) void k_transpose_v(const ushort* __restrict__ V,
                                                     ushort* __restrict__ VT) {
    __shared__ ushort tile[64][72];
    const int bh = blockIdx.y, t0 = blockIdx.x * 64;
    const int tid = threadIdx.x;
    const ushort* Vb = V + (size_t)bh * 4096 * 64;
    ushort* Ob = VT + (size_t)bh * 64 * 4096;
    const int r = tid >> 2, cb = (tid & 3) * 16;
    uint4 a = *(const uint4*)&Vb[(size_t)(t0 + r) * 64 + cb];
    uint4 b = *(const uint4*)&Vb[(size_t)(t0 + r) * 64 + cb + 8];
    *(uint4*)&tile[r][cb] = a;
    *(uint4*)&tile[r][cb + 8] = b;
    __syncthreads();
    const int d = tid >> 2, tc = (tid & 3) * 16;
    ushort vals[16];
#pragma unroll
    for (int j = 0; j < 16; ++j) vals[j] = tile[tc + j][d];
    *(uint4*)&Ob[(size_t)d * 4096 + t0 + tc]     = *(const uint4*)&vals[0];
    *(uint4*)&Ob[(size_t)d * 4096 + t0 + tc + 8] = *(const uint4*)&vals[8];
}

// ---------------- bf16 GEMM, A [M][K] x BT [N][K] (=B^T), 128x128 tile ----------------
// MODE 0: epilogue scatters Q(*0.125)/K/V bf16 to [B*H][T][D], bias=bqkv
// MODE 1: epilogue writes f32 out[M][512] + bias
template <int MODE>
__global__ __launch_bounds__(256) void k_gemm(const ushort* __restrict__ A,
                                              const ushort* __restrict__ BT,
                                              const float* __restrict__ bias,
                                              float* __restrict__ outF,
                                              ushort* __restrict__ Qp,
                                              ushort* __restrict__ Kp,
                                              ushort* __restrict__ Vp,
                                              int K) {
    __shared__ __align__(16) ushort lA[128 * 32];
    __shared__ __align__(16) ushort lB[128 * 32];
    const int tid = threadIdx.x;
    const int lane = tid & 63, lr = lane & 15, lg = lane >> 4;
    const int wid = tid >> 6, wm = wid >> 1, wn = wid & 1;
    const int m0 = blockIdx.x * 128, n0 = blockIdx.y * 128;

    const ushort* ga = A + (size_t)(m0 + (tid >> 2)) * K + (tid & 3) * 8;
    const ushort* gb = BT + (size_t)(n0 + (tid >> 2)) * K + (tid & 3) * 8;
    const size_t rstep = (size_t)64 * K;

    f32x4 zero = {0.f, 0.f, 0.f, 0.f};
    f32x4 acc[4][4];
#pragma unroll
    for (int i = 0; i < 4; ++i)
#pragma unroll
        for (int j = 0; j < 4; ++j) acc[i][j] = zero;

    for (int k0 = 0; k0 < K; k0 += 32) {
        glds16(ga + k0,         &lA[tid * 8]);
        glds16(ga + k0 + rstep, &lA[2048 + tid * 8]);
        glds16(gb + k0,         &lB[tid * 8]);
        glds16(gb + k0 + rstep, &lB[2048 + tid * 8]);
        __syncthreads();
        bf16x8 af[4], bfr[4];
#pragma unroll
        for (int m = 0; m < 4; ++m)
            af[m] = *(const bf16x8*)&lA[(wm * 64 + m * 16 + lr) * 32 + lg * 8];
#pragma unroll
        for (int n = 0; n < 4; ++n)
            bfr[n] = *(const bf16x8*)&lB[(wn * 64 + n * 16 + lr) * 32 + lg * 8];
#pragma unroll
        for (int m = 0; m < 4; ++m)
#pragma unroll
            for (int n = 0; n < 4; ++n)
                acc[m][n] = __builtin_amdgcn_mfma_f32_16x16x32_bf16(af[m], bfr[n], acc[m][n], 0, 0, 0);
        __syncthreads();
    }

#pragma unroll
    for (int n = 0; n < 4; ++n) {
        const int gn = n0 + wn * 64 + n * 16 + lr;
        const float bv = bias[gn];
#pragma unroll
        for (int m = 0; m < 4; ++m) {
#pragma unroll
            for (int r = 0; r < 4; ++r) {
                const int gm = m0 + wm * 64 + m * 16 + lg * 4 + r;
                float v = acc[m][n][r] + bv;
                if (MODE == 0) {
                    const int sec = gn >> 9, c = gn & 511;
                    const int h = c >> 6, d = c & 63;
                    const int b = gm >> 12, t = gm & 4095;
                    const size_t idx = ((size_t)(b * 8 + h) * 4096 + t) * 64 + d;
                    if (sec == 0)      Qp[idx] = f2b(v * 0.125f);
                    else if (sec == 1) Kp[idx] = f2b(v);
                    else               Vp[idx] = f2b(v);
                } else {
                    outF[(size_t)gm * 512 + gn] = v;
                }
            }
        }
    }
}

// ---------------- flash attention: Q,K [bh][T][D], VT [bh][D][T] -> out bf16 [B][T][C] ----------------
__global__ __launch_bounds__(256) void k_attn(const ushort* __restrict__ Q,
                                              const ushort* __restrict__ Kt,
                                              const ushort* __restrict__ VT,
                                              ushort* __restrict__ Outp) {
    __shared__ __align__(16) ushort sK[32 * 64];      // [kv][d]
    __shared__ __align__(16) ushort sV[64 * 32];      // [d][kv]
    __shared__ __align__(16) ushort sP[4][16 * 32];   // per-wave [qr][kv]
    const int tid = threadIdx.x, wid = tid >> 6, lane = tid & 63;
    const int lr = lane & 15, lg = lane >> 4;
    const int qt = (gridDim.x - 1) - blockIdx.x;      // heavy tiles first
    const int bh = blockIdx.y;
    const int q0 = qt * 64;
    const size_t base = (size_t)bh * 4096 * 64;
    const ushort* Qb = Q + base;
    const ushort* Kb = Kt + base;
    const ushort* Vb = VT + base;

    const int qrow = q0 + wid * 16 + lr;              // A-frag row
    bf16x8 aq0 = *(const bf16x8*)&Qb[(size_t)qrow * 64 + lg * 8];
    bf16x8 aq1 = *(const bf16x8*)&Qb[(size_t)qrow * 64 + 32 + lg * 8];

    f32x4 zero = {0.f, 0.f, 0.f, 0.f};
    f32x4 oacc[4];
#pragma unroll
    for (int nt = 0; nt < 4; ++nt) oacc[nt] = zero;
    float mrun[4], lrun[4];
#pragma unroll
    for (int r = 0; r < 4; ++r) { mrun[r] = -1e30f; lrun[r] = 0.f; }
    const int myrow = q0 + wid * 16 + lg * 4;         // acc row base (+r)
    const int nkv = (q0 + 64) >> 5;

    for (int it = 0; it < nkv; ++it) {
        const int kv0 = it * 32;
        glds16(Kb + (size_t)(kv0 + (tid >> 3)) * 64 + (tid & 7) * 8, &sK[tid * 8]);
        glds16(Vb + (size_t)(tid >> 2) * 4096 + kv0 + (tid & 3) * 8, &sV[tid * 8]);
        __syncthreads();

        f32x4 s0 = zero, s1 = zero;
        {
            bf16x8 bk;
            bk = *(const bf16x8*)&sK[lr * 64 + lg * 8];
            s0 = __builtin_amdgcn_mfma_f32_16x16x32_bf16(aq0, bk, s0, 0, 0, 0);
            bk = *(const bf16x8*)&sK[lr * 64 + 32 + lg * 8];
            s0 = __builtin_amdgcn_mfma_f32_16x16x32_bf16(aq1, bk, s0, 0, 0, 0);
            bk = *(const bf16x8*)&sK[(16 + lr) * 64 + lg * 8];
            s1 = __builtin_amdgcn_mfma_f32_16x16x32_bf16(aq0, bk, s1, 0, 0, 0);
            bk = *(const bf16x8*)&sK[(16 + lr) * 64 + 32 + lg * 8];
            s1 = __builtin_amdgcn_mfma_f32_16x16x32_bf16(aq1, bk, s1, 0, 0, 0);
        }
        if (kv0 + 31 > q0 + wid * 16) {               // diagonal/above: mask
#pragma unroll
            for (int r = 0; r < 4; ++r) {
                const int row = myrow + r;
                if (kv0 + lr > row)      s0[r] = -1e30f;
                if (kv0 + 16 + lr > row) s1[r] = -1e30f;
            }
        }
        // wave-parallel online softmax over the 32 kv cols
        float ml[4];
#pragma unroll
        for (int r = 0; r < 4; ++r) ml[r] = fmaxf(s0[r], s1[r]);
#pragma unroll
        for (int off = 1; off < 16; off <<= 1)
#pragma unroll
            for (int r = 0; r < 4; ++r) ml[r] = fmaxf(ml[r], __shfl_xor(ml[r], off));
        float al[4], p0[4], p1[4], ll[4];
#pragma unroll
        for (int r = 0; r < 4; ++r) {
            float mn = fmaxf(mrun[r], ml[r]);
            al[r] = exp2f((mrun[r] - mn) * LOG2E);
            mrun[r] = mn;
            p0[r] = exp2f((s0[r] - mn) * LOG2E);
            p1[r] = exp2f((s1[r] - mn) * LOG2E);
            ll[r] = p0[r] + p1[r];
        }
#pragma unroll
        for (int off = 1; off < 16; off <<= 1)
#pragma unroll
            for (int r = 0; r < 4; ++r) ll[r] += __shfl_xor(ll[r], off);
#pragma unroll
        for (int r = 0; r < 4; ++r) lrun[r] = lrun[r] * al[r] + ll[r];
#pragma unroll
        for (int nt = 0; nt < 4; ++nt)
#pragma unroll
            for (int r = 0; r < 4; ++r) oacc[nt][r] *= al[r];

        // P (acc layout) -> LDS -> A-frag layout
        ushort* myP = &sP[wid][0];
#pragma unroll
        for (int r = 0; r < 4; ++r) {
            myP[(lg * 4 + r) * 32 + lr]      = f2b(p0[r]);
            myP[(lg * 4 + r) * 32 + 16 + lr] = f2b(p1[r]);
        }
        asm volatile("s_waitcnt lgkmcnt(0)" ::: "memory");
        bf16x8 ap = *(const bf16x8*)&myP[lr * 32 + lg * 8];
#pragma unroll
        for (int nt = 0; nt < 4; ++nt) {
            bf16x8 bv = *(const bf16x8*)&sV[(nt * 16 + lr) * 32 + lg * 8];
            oacc[nt] = __builtin_amdgcn_mfma_f32_16x16x32_bf16(ap, bv, oacc[nt], 0, 0, 0);
        }
        __syncthreads();
    }

    const int b = bh >> 3, h = bh & 7;
#pragma unroll
    for (int nt = 0; nt < 4; ++nt)
#pragma unroll
        for (int r = 0; r < 4; ++r) {
            const int t = myrow + r;
            const float ov = oacc[nt][r] / lrun[r];
            Outp[((size_t)b * 4096 + t) * 512 + h * 64 + nt * 16 + lr] = f2b(ov);
        }
}

extern "C" void kernel_launch(void* const* d_in, const int* in_sizes, int n_in,
                              void* d_out, int out_size, void* d_ws, size_t ws_size,
                              hipStream_t stream) {
    const float* x    = (const float*)d_in[0];
    const float* Wqkv = (const float*)d_in[1];
    const float* bqkv = (const float*)d_in[2];
    const float* Wout = (const float*)d_in[3];
    const float* bout = (const float*)d_in[4];
    float* out = (float*)d_out;

    char* ws = (char*)d_ws;
    ushort* xb    = (ushort*)(ws);                 // 8 MB (reused as attn out)
    ushort* wqkvT = (ushort*)(ws + 8388608);       // 1.5 MB
    ushort* woutT = (ushort*)(ws + 9961472);       // 0.5 MB
    ushort* Qp    = (ushort*)(ws + 10485760);      // 8 MB
    ushort* Kp    = (ushort*)(ws + 18874368);      // 8 MB
    ushort* Vp    = (ushort*)(ws + 27262976);      // 8 MB
    ushort* VTp   = (ushort*)(ws + 35651584);      // 8 MB  (total 44 MB)

    k_convert<<<2048, 256, 0, stream>>>(x, xb, 524288);
    k_transpose_w<<<dim3(48, 16), dim3(32, 8), 0, stream>>>(Wqkv, wqkvT, 512, 1536);
    k_transpose_w<<<dim3(16, 16), dim3(32, 8), 0, stream>>>(Wout, woutT, 512, 512);
    k_gemm<0><<<dim3(64, 12), 256, 0, stream>>>(xb, wqkvT, bqkv, nullptr, Qp, Kp, Vp, 512);
    k_transpose_v<<<dim3(64, 16), 256, 0, stream>>>(Vp, VTp);
    k_attn<<<dim3(64, 16), 256, 0, stream>>>(Qp, Kp, VTp, xb);
    k_gemm<1><<<dim3(64, 4), 256, 0, stream>>>(xb, woutT, bout, out, nullptr, nullptr, nullptr, 512);
}

// Round 3
// 201.157 us; speedup vs baseline: 2.0316x; 2.0316x over previous
//
#include <hip/hip_runtime.h>
#include <hip/hip_bf16.h>
#include <cstdint>
#include <cstddef>

typedef __attribute__((ext_vector_type(8))) __bf16 bf16x8;
typedef __attribute__((ext_vector_type(4))) float f32x4;
typedef __attribute__((ext_vector_type(16))) float f32x16;

#define LOG2E 1.4426950408889634f

__device__ __forceinline__ ushort f2b(float x) {
    union { float f; uint32_t u; } v; v.f = x;
    uint32_t r = v.u + 0x7FFFu + ((v.u >> 16) & 1u);   // RNE
    return (ushort)(r >> 16);
}

__device__ __forceinline__ void glds16(const void* g, void* l) {
    __builtin_amdgcn_global_load_lds(
        (const __attribute__((address_space(1))) void*)g,
        (__attribute__((address_space(3))) void*)l, 16, 0, 0);
}

__device__ __forceinline__ uint32_t cvt_pk_bf16(float lo, float hi) {
    uint32_t r;
    asm("v_cvt_pk_bf16_f32 %0, %1, %2" : "=v"(r) : "v"(lo), "v"(hi));
    return r;
}

__device__ __forceinline__ f32x16 z16() {
    f32x16 v;
#pragma unroll
    for (int i = 0; i < 16; ++i) v[i] = 0.f;
    return v;
}

// ---------------- convert f32 -> bf16, 8 elems/thread ----------------
__global__ __launch_bounds__(256) void k_convert(const float* __restrict__ in,
                                                 ushort* __restrict__ out, int n8) {
    int i = blockIdx.x * 256 + threadIdx.x;
    if (i >= n8) return;
    const float4* p = (const float4*)in + (size_t)i * 2;
    float4 a = p[0], b = p[1];
    ushort o[8] = { f2b(a.x), f2b(a.y), f2b(a.z), f2b(a.w),
                    f2b(b.x), f2b(b.y), f2b(b.z), f2b(b.w) };
    *(uint4*)(out + (size_t)i * 8) = *(const uint4*)o;
}

// ------------- transpose-convert: in f32 [R][C] -> out bf16 [C][R] -------------
__global__ __launch_bounds__(256) void k_transpose_w(const float* __restrict__ in,
                                                     ushort* __restrict__ out,
                                                     int R, int C) {
    __shared__ float tile[32][33];
    int c0 = blockIdx.x * 32, r0 = blockIdx.y * 32;
    int tx = threadIdx.x, ty = threadIdx.y;   // (32,8)
#pragma unroll
    for (int i = 0; i < 32; i += 8)
        tile[ty + i][tx] = in[(size_t)(r0 + ty + i) * C + c0 + tx];
    __syncthreads();
#pragma unroll
    for (int i = 0; i < 32; i += 8)
        out[(size_t)(c0 + ty + i) * R + r0 + tx] = f2b(tile[tx][ty + i]);
}

// ------------- transpose V [bh][T][D] bf16 -> VT [bh][D][T] bf16 -------------
__global__ __launch_bounds__(256) void k_transpose_v(const ushort* __restrict__ V,
                                                     ushort* __restrict__ VT) {
    __shared__ ushort tile[64][72];
    const int bh = blockIdx.y, t0 = blockIdx.x * 64;
    const int tid = threadIdx.x;
    const ushort* Vb = V + (size_t)bh * 4096 * 64;
    ushort* Ob = VT + (size_t)bh * 64 * 4096;
    const int r = tid >> 2, cb = (tid & 3) * 16;
    uint4 a = *(const uint4*)&Vb[(size_t)(t0 + r) * 64 + cb];
    uint4 b = *(const uint4*)&Vb[(size_t)(t0 + r) * 64 + cb + 8];
    *(uint4*)&tile[r][cb] = a;
    *(uint4*)&tile[r][cb + 8] = b;
    __syncthreads();
    const int d = tid >> 2, tc = (tid & 3) * 16;
    ushort vals[16];
#pragma unroll
    for (int j = 0; j < 16; ++j) vals[j] = tile[tc + j][d];
    *(uint4*)&Ob[(size_t)d * 4096 + t0 + tc]     = *(const uint4*)&vals[0];
    *(uint4*)&Ob[(size_t)d * 4096 + t0 + tc + 8] = *(const uint4*)&vals[8];
}

// ---------------- bf16 GEMM, A [M][K] x BT [N][K] (=B^T), 128x128 tile ----------------
template <int MODE>
__global__ __launch_bounds__(256) void k_gemm(const ushort* __restrict__ A,
                                              const ushort* __restrict__ BT,
                                              const float* __restrict__ bias,
                                              float* __restrict__ outF,
                                              ushort* __restrict__ Qp,
                                              ushort* __restrict__ Kp,
                                              ushort* __restrict__ Vp,
                                              int K) {
    __shared__ __align__(16) ushort lA[128 * 32];
    __shared__ __align__(16) ushort lB[128 * 32];
    const int tid = threadIdx.x;
    const int lane = tid & 63, lr = lane & 15, lg = lane >> 4;
    const int wid = tid >> 6, wm = wid >> 1, wn = wid & 1;
    const int m0 = blockIdx.x * 128, n0 = blockIdx.y * 128;

    const ushort* ga = A + (size_t)(m0 + (tid >> 2)) * K + (tid & 3) * 8;
    const ushort* gb = BT + (size_t)(n0 + (tid >> 2)) * K + (tid & 3) * 8;
    const size_t rstep = (size_t)64 * K;

    f32x4 zero = {0.f, 0.f, 0.f, 0.f};
    f32x4 acc[4][4];
#pragma unroll
    for (int i = 0; i < 4; ++i)
#pragma unroll
        for (int j = 0; j < 4; ++j) acc[i][j] = zero;

    for (int k0 = 0; k0 < K; k0 += 32) {
        glds16(ga + k0,         &lA[tid * 8]);
        glds16(ga + k0 + rstep, &lA[2048 + tid * 8]);
        glds16(gb + k0,         &lB[tid * 8]);
        glds16(gb + k0 + rstep, &lB[2048 + tid * 8]);
        __syncthreads();
        bf16x8 af[4], bfr[4];
#pragma unroll
        for (int m = 0; m < 4; ++m)
            af[m] = *(const bf16x8*)&lA[(wm * 64 + m * 16 + lr) * 32 + lg * 8];
#pragma unroll
        for (int n = 0; n < 4; ++n)
            bfr[n] = *(const bf16x8*)&lB[(wn * 64 + n * 16 + lr) * 32 + lg * 8];
#pragma unroll
        for (int m = 0; m < 4; ++m)
#pragma unroll
            for (int n = 0; n < 4; ++n)
                acc[m][n] = __builtin_amdgcn_mfma_f32_16x16x32_bf16(af[m], bfr[n], acc[m][n], 0, 0, 0);
        __syncthreads();
    }

#pragma unroll
    for (int n = 0; n < 4; ++n) {
        const int gn = n0 + wn * 64 + n * 16 + lr;
        const float bv = bias[gn];
#pragma unroll
        for (int m = 0; m < 4; ++m) {
#pragma unroll
            for (int r = 0; r < 4; ++r) {
                const int gm = m0 + wm * 64 + m * 16 + lg * 4 + r;
                float v = acc[m][n][r] + bv;
                if (MODE == 0) {
                    const int sec = gn >> 9, c = gn & 511;
                    const int h = c >> 6, d = c & 63;
                    const int b = gm >> 12, t = gm & 4095;
                    const size_t idx = ((size_t)(b * 8 + h) * 4096 + t) * 64 + d;
                    if (sec == 0)      Qp[idx] = f2b(v * 0.125f);   // exact in bf16
                    else if (sec == 1) Kp[idx] = f2b(v);
                    else               Vp[idx] = f2b(v);
                } else {
                    outF[(size_t)gm * 512 + gn] = v;
                }
            }
        }
    }
}

// ---------------- flash attention, 4 waves x 32 q-rows, KVBLK=64, swapped QK^T ----------------
// Q,K: [bh][T][64] bf16 (Q pre-scaled by 0.125), VT: [bh][64][T] bf16
// out: bf16 [B][T][512]
__global__ __launch_bounds__(256) void k_attn(const ushort* __restrict__ Q,
                                              const ushort* __restrict__ K,
                                              const ushort* __restrict__ VT,
                                              ushort* __restrict__ Outp) {
    __shared__ __align__(16) ushort sm[16384];   // 2 bufs x (K 8KB + V 8KB)
    const int tid = threadIdx.x;
    const int lane = tid & 63, w = tid >> 6;
    const int lg2 = lane >> 5, l31 = lane & 31, l7 = lane & 7;
    const int qt = 31 - (int)blockIdx.x;          // heavy tiles first
    const int bh = blockIdx.y;
    const int q0 = qt * 128;
    const int qbase = q0 + w * 32;
    const size_t base = (size_t)bh * 4096 * 64;
    const ushort* Kb = K + base;
    const ushort* Vb = VT + base;                 // [64][4096]
    const ushort* Qb = Q + base;

    // Q fragments: B-operand of 32x32x16 (col = lane&31 -> q row, k = (lane>>5)*8+e)
    bf16x8 qf[4];
#pragma unroll
    for (int ks = 0; ks < 4; ++ks)
        qf[ks] = *(const bf16x8*)&Qb[(size_t)(qbase + l31) * 64 + ks * 16 + lg2 * 8];
    asm volatile("" ::: "memory");

    const int srow = lane >> 3;                   // 0..7
    const int sslot = l7 ^ srow;                  // pre-swizzled global slot (rule 21)

    auto STAGE = [&](int buf, int kv0) {
#pragma unroll
        for (int j = 0; j < 2; ++j) {
            const int r = j * 32 + w * 8 + srow;  // kv row
            glds16(Kb + (size_t)(kv0 + r) * 64 + sslot * 8,
                   (char*)sm + buf * 16384 + j * 4096 + w * 1024);
        }
#pragma unroll
        for (int j = 0; j < 2; ++j) {
            const int r = j * 32 + w * 8 + srow;  // d row
            glds16(Vb + (size_t)r * 4096 + kv0 + sslot * 8,
                   (char*)sm + buf * 16384 + 8192 + j * 4096 + w * 1024);
        }
    };

    f32x16 oacc0 = z16(), oacc1 = z16();          // O^T: col=q (lane&31), rows=d pattern
    float mrun = -1e30f, lrun = 0.f;
    const int NT = 2 * qt + 2;

    STAGE(0, 0);
    for (int it = 0; it < NT; ++it) {
        const int kv0 = it * 64;
        const int bsel = it & 1;
        if (it + 1 < NT) STAGE(bsel ^ 1, kv0 + 64);
        __syncthreads();                          // drain: buf[bsel] fully resident

        const bool live0 = (kv0 <= qbase + 31);
        const bool live1 = (kv0 + 32 <= qbase + 31);
        if (live0) {
            const ushort* bK = sm + bsel * 8192;
            const ushort* bV = bK + 4096;

            // S^T = K x Q^T : col = q = lane&31, kv rows reg-distributed
            f32x16 st0 = z16(), st1 = z16();
#pragma unroll
            for (int ks = 0; ks < 4; ++ks) {
                bf16x8 kf = *(const bf16x8*)&bK[l31 * 64 + (((2 * ks + lg2) ^ l7)) * 8];
                st0 = __builtin_amdgcn_mfma_f32_32x32x16_bf16(kf, qf[ks], st0, 0, 0, 0);
            }
            if (live1) {
#pragma unroll
                for (int ks = 0; ks < 4; ++ks) {
                    bf16x8 kf = *(const bf16x8*)&bK[(32 + l31) * 64 + (((2 * ks + lg2) ^ l7)) * 8];
                    st1 = __builtin_amdgcn_mfma_f32_32x32x16_bf16(kf, qf[ks], st1, 0, 0, 0);
                }
            }
            if (kv0 == qbase) {                   // diagonal tile 0
#pragma unroll
                for (int r = 0; r < 16; ++r) {
                    const int rowk = (r & 3) + 8 * (r >> 2) + 4 * lg2;
                    if (rowk > l31) st0[r] = -1e30f;
                }
            }
            if (live1 && kv0 + 32 == qbase) {     // diagonal tile 1
#pragma unroll
                for (int r = 0; r < 16; ++r) {
                    const int rowk = (r & 3) + 8 * (r >> 2) + 4 * lg2;
                    if (rowk > l31) st1[r] = -1e30f;
                }
            }

            // in-lane row max (4 chains), then cross-half via shfl
            float m0 = -1e30f, m1 = -1e30f, m2 = -1e30f, m3 = -1e30f;
#pragma unroll
            for (int r = 0; r < 16; r += 4) {
                m0 = fmaxf(m0, st0[r]);     m1 = fmaxf(m1, st0[r + 1]);
                m2 = fmaxf(m2, st0[r + 2]); m3 = fmaxf(m3, st0[r + 3]);
            }
            if (live1) {
#pragma unroll
                for (int r = 0; r < 16; r += 4) {
                    m0 = fmaxf(m0, st1[r]);     m1 = fmaxf(m1, st1[r + 1]);
                    m2 = fmaxf(m2, st1[r + 2]); m3 = fmaxf(m3, st1[r + 3]);
                }
            }
            float tmax = fmaxf(fmaxf(m0, m1), fmaxf(m2, m3));
            tmax = fmaxf(tmax, __shfl_xor(tmax, 32));

            const float mnew = fmaxf(mrun, tmax);
            const float al = __builtin_amdgcn_exp2f((mrun - mnew) * LOG2E);
            const float ml2 = mnew * LOG2E;
            mrun = mnew;

            float s0 = 0.f, s1 = 0.f, s2 = 0.f, s3 = 0.f;
#pragma unroll
            for (int r = 0; r < 16; r += 4) {
                st0[r]     = __builtin_amdgcn_exp2f(fmaf(st0[r],     LOG2E, -ml2)); s0 += st0[r];
                st0[r + 1] = __builtin_amdgcn_exp2f(fmaf(st0[r + 1], LOG2E, -ml2)); s1 += st0[r + 1];
                st0[r + 2] = __builtin_amdgcn_exp2f(fmaf(st0[r + 2], LOG2E, -ml2)); s2 += st0[r + 2];
                st0[r + 3] = __builtin_amdgcn_exp2f(fmaf(st0[r + 3], LOG2E, -ml2)); s3 += st0[r + 3];
            }
            if (live1) {
#pragma unroll
                for (int r = 0; r < 16; r += 4) {
                    st1[r]     = __builtin_amdgcn_exp2f(fmaf(st1[r],     LOG2E, -ml2)); s0 += st1[r];
                    st1[r + 1] = __builtin_amdgcn_exp2f(fmaf(st1[r + 1], LOG2E, -ml2)); s1 += st1[r + 1];
                    st1[r + 2] = __builtin_amdgcn_exp2f(fmaf(st1[r + 2], LOG2E, -ml2)); s2 += st1[r + 2];
                    st1[r + 3] = __builtin_amdgcn_exp2f(fmaf(st1[r + 3], LOG2E, -ml2)); s3 += st1[r + 3];
                }
            }
            float psum = (s0 + s1) + (s2 + s3);
            psum += __shfl_xor(psum, 32);
            lrun = lrun * al + psum;
#pragma unroll
            for (int r = 0; r < 16; ++r) { oacc0[r] *= al; oacc1[r] *= al; }

            // P -> bf16 B-frag via cvt_pk + cross-half shfl, then PV (O^T = V^T x P^T)
#pragma unroll
            for (int stp = 0; stp < 4; ++stp) {
                if (stp >= 2 && !live1) continue;
                const int h = stp & 1;
                uint32_t a0, a1, b0, b1;
                if (stp < 2) {
                    a0 = cvt_pk_bf16(st0[h * 8 + 0], st0[h * 8 + 1]);
                    a1 = cvt_pk_bf16(st0[h * 8 + 2], st0[h * 8 + 3]);
                    b0 = cvt_pk_bf16(st0[h * 8 + 4], st0[h * 8 + 5]);
                    b1 = cvt_pk_bf16(st0[h * 8 + 6], st0[h * 8 + 7]);
                } else {
                    a0 = cvt_pk_bf16(st1[h * 8 + 0], st1[h * 8 + 1]);
                    a1 = cvt_pk_bf16(st1[h * 8 + 2], st1[h * 8 + 3]);
                    b0 = cvt_pk_bf16(st1[h * 8 + 4], st1[h * 8 + 5]);
                    b1 = cvt_pk_bf16(st1[h * 8 + 6], st1[h * 8 + 7]);
                }
                const uint32_t pa0 = (uint32_t)__shfl_xor((int)a0, 32);
                const uint32_t pa1 = (uint32_t)__shfl_xor((int)a1, 32);
                const uint32_t pb0 = (uint32_t)__shfl_xor((int)b0, 32);
                const uint32_t pb1 = (uint32_t)__shfl_xor((int)b1, 32);
                union { uint32_t u[4]; bf16x8 v; } pk;
                pk.u[0] = lg2 ? pb0 : a0;
                pk.u[1] = lg2 ? pb1 : a1;
                pk.u[2] = lg2 ? b0 : pa0;
                pk.u[3] = lg2 ? b1 : pa1;
                const int vs = (((2 * stp + lg2) ^ l7)) * 8;
                bf16x8 vf0 = *(const bf16x8*)&bV[l31 * 64 + vs];
                bf16x8 vf1 = *(const bf16x8*)&bV[(32 + l31) * 64 + vs];
                oacc0 = __builtin_amdgcn_mfma_f32_32x32x16_bf16(vf0, pk.v, oacc0, 0, 0, 0);
                oacc1 = __builtin_amdgcn_mfma_f32_32x32x16_bf16(vf1, pk.v, oacc1, 0, 0, 0);
            }
        }
        __syncthreads();                          // all reads of buf[bsel] done
    }

    // epilogue: O^T -> LDS transpose (per-warp region) -> coalesced global store
    const float inv = 1.0f / lrun;
    ushort* ep = sm + w * 2304;                   // [32 q][72] ushort
#pragma unroll
    for (int r = 0; r < 16; ++r) {
        const int dd = (r & 3) + 8 * (r >> 2) + 4 * lg2;
        ep[l31 * 72 + dd]      = f2b(oacc0[r] * inv);
        ep[l31 * 72 + 32 + dd] = f2b(oacc1[r] * inv);
    }
    asm volatile("s_waitcnt lgkmcnt(0)" ::: "memory");
    __builtin_amdgcn_sched_barrier(0);
    const int qq = lane >> 1, half = lane & 1;
    const int bb = bh >> 3, hh = bh & 7;
    const int tg = q0 + w * 32 + qq;
    ushort* op = Outp + ((size_t)(bb * 4096 + tg) * 512 + hh * 64 + half * 32);
#pragma unroll
    for (int j = 0; j < 4; ++j) {
        uint4 v = *(const uint4*)&ep[qq * 72 + half * 32 + j * 8];
        *(uint4*)&op[j * 8] = v;
    }
}

extern "C" void kernel_launch(void* const* d_in, const int* in_sizes, int n_in,
                              void* d_out, int out_size, void* d_ws, size_t ws_size,
                              hipStream_t stream) {
    const float* x    = (const float*)d_in[0];
    const float* Wqkv = (const float*)d_in[1];
    const float* bqkv = (const float*)d_in[2];
    const float* Wout = (const float*)d_in[3];
    const float* bout = (const float*)d_in[4];
    float* out = (float*)d_out;

    char* ws = (char*)d_ws;
    ushort* xb    = (ushort*)(ws);                 // 8 MB (x bf16, later attn out)
    ushort* wqkvT = (ushort*)(ws + 8388608);       // 1.5 MB
    ushort* woutT = (ushort*)(ws + 9961472);       // 0.5 MB
    ushort* Qp    = (ushort*)(ws + 10485760);      // 8 MB
    ushort* Kp    = (ushort*)(ws + 18874368);      // 8 MB
    ushort* Vp    = (ushort*)(ws + 27262976);      // 8 MB
    ushort* VTp   = (ushort*)(ws + 35651584);      // 8 MB  (total 44 MB)

    k_convert<<<2048, 256, 0, stream>>>(x, xb, 524288);
    k_transpose_w<<<dim3(48, 16), dim3(32, 8), 0, stream>>>(Wqkv, wqkvT, 512, 1536);
    k_transpose_w<<<dim3(16, 16), dim3(32, 8), 0, stream>>>(Wout, woutT, 512, 512);
    k_gemm<0><<<dim3(64, 12), 256, 0, stream>>>(xb, wqkvT, bqkv, nullptr, Qp, Kp, Vp, 512);
    k_transpose_v<<<dim3(64, 16), 256, 0, stream>>>(Vp, VTp);
    k_attn<<<dim3(32, 16), 256, 0, stream>>>(Qp, Kp, VTp, xb);
    k_gemm<1><<<dim3(64, 4), 256, 0, stream>>>(xb, woutT, bout, out, nullptr, nullptr, nullptr, 512);
}

// Round 4
// 163.835 us; speedup vs baseline: 2.4944x; 1.2278x over previous
//
#include <hip/hip_runtime.h>
#include <hip/hip_bf16.h>
#include <cstdint>
#include <cstddef>

typedef __attribute__((ext_vector_type(8))) __bf16 bf16x8;
typedef __attribute__((ext_vector_type(4))) float f32x4;
typedef __attribute__((ext_vector_type(16))) float f32x16;

#define LOG2E 1.4426950408889634f

__device__ __forceinline__ ushort f2b(float x) {
    union { float f; uint32_t u; } v; v.f = x;
    uint32_t r = v.u + 0x7FFFu + ((v.u >> 16) & 1u);   // RNE
    return (ushort)(r >> 16);
}

__device__ __forceinline__ void glds16(const void* g, void* l) {
    __builtin_amdgcn_global_load_lds(
        (const __attribute__((address_space(1))) void*)g,
        (__attribute__((address_space(3))) void*)l, 16, 0, 0);
}

__device__ __forceinline__ uint32_t cvt_pk_bf16(float lo, float hi) {
    uint32_t r;
    asm("v_cvt_pk_bf16_f32 %0, %1, %2" : "=v"(r) : "v"(lo), "v"(hi));
    return r;
}

__device__ __forceinline__ f32x16 z16() {
    f32x16 v;
#pragma unroll
    for (int i = 0; i < 16; ++i) v[i] = 0.f;
    return v;
}

// ---------------- convert f32 -> bf16, 8 elems/thread ----------------
__global__ __launch_bounds__(256) void k_convert(const float* __restrict__ in,
                                                 ushort* __restrict__ out, int n8) {
    int i = blockIdx.x * 256 + threadIdx.x;
    if (i >= n8) return;
    const float4* p = (const float4*)in + (size_t)i * 2;
    float4 a = p[0], b = p[1];
    ushort o[8] = { f2b(a.x), f2b(a.y), f2b(a.z), f2b(a.w),
                    f2b(b.x), f2b(b.y), f2b(b.z), f2b(b.w) };
    *(uint4*)(out + (size_t)i * 8) = *(const uint4*)o;
}

// ------------- transpose-convert: in f32 [R][C] -> out bf16 [C][R] -------------
__global__ __launch_bounds__(256) void k_transpose_w(const float* __restrict__ in,
                                                     ushort* __restrict__ out,
                                                     int R, int C) {
    __shared__ float tile[32][33];
    int c0 = blockIdx.x * 32, r0 = blockIdx.y * 32;
    int tx = threadIdx.x, ty = threadIdx.y;   // (32,8)
#pragma unroll
    for (int i = 0; i < 32; i += 8)
        tile[ty + i][tx] = in[(size_t)(r0 + ty + i) * C + c0 + tx];
    __syncthreads();
#pragma unroll
    for (int i = 0; i < 32; i += 8)
        out[(size_t)(c0 + ty + i) * R + r0 + tx] = f2b(tile[tx][ty + i]);
}

// ---------------- bf16 GEMM, A [M][K] x BT [N][K] (=B^T), 128x128 tile ----------------
// MODE 0: epilogue scatters Q(*0.125)/K bf16 to [B*H][T][D] and V directly
//         TRANSPOSED to VT [B*H][D][T] (8B t-contiguous stores), bias=bqkv
// MODE 1: epilogue writes f32 out[M][512] + bias
template <int MODE>
__global__ __launch_bounds__(256) void k_gemm(const ushort* __restrict__ A,
                                              const ushort* __restrict__ BT,
                                              const float* __restrict__ bias,
                                              float* __restrict__ outF,
                                              ushort* __restrict__ Qp,
                                              ushort* __restrict__ Kp,
                                              ushort* __restrict__ VTp,
                                              int K) {
    __shared__ __align__(16) ushort lA[128 * 32];
    __shared__ __align__(16) ushort lB[128 * 32];
    const int tid = threadIdx.x;
    const int lane = tid & 63, lr = lane & 15, lg = lane >> 4;
    const int wid = tid >> 6, wm = wid >> 1, wn = wid & 1;
    const int m0 = blockIdx.x * 128, n0 = blockIdx.y * 128;

    const ushort* ga = A + (size_t)(m0 + (tid >> 2)) * K + (tid & 3) * 8;
    const ushort* gb = BT + (size_t)(n0 + (tid >> 2)) * K + (tid & 3) * 8;
    const size_t rstep = (size_t)64 * K;

    f32x4 zero = {0.f, 0.f, 0.f, 0.f};
    f32x4 acc[4][4];
#pragma unroll
    for (int i = 0; i < 4; ++i)
#pragma unroll
        for (int j = 0; j < 4; ++j) acc[i][j] = zero;

    for (int k0 = 0; k0 < K; k0 += 32) {
        glds16(ga + k0,         &lA[tid * 8]);
        glds16(ga + k0 + rstep, &lA[2048 + tid * 8]);
        glds16(gb + k0,         &lB[tid * 8]);
        glds16(gb + k0 + rstep, &lB[2048 + tid * 8]);
        __syncthreads();
        bf16x8 af[4], bfr[4];
#pragma unroll
        for (int m = 0; m < 4; ++m)
            af[m] = *(const bf16x8*)&lA[(wm * 64 + m * 16 + lr) * 32 + lg * 8];
#pragma unroll
        for (int n = 0; n < 4; ++n)
            bfr[n] = *(const bf16x8*)&lB[(wn * 64 + n * 16 + lr) * 32 + lg * 8];
#pragma unroll
        for (int m = 0; m < 4; ++m)
#pragma unroll
            for (int n = 0; n < 4; ++n)
                acc[m][n] = __builtin_amdgcn_mfma_f32_16x16x32_bf16(af[m], bfr[n], acc[m][n], 0, 0, 0);
        __syncthreads();
    }

#pragma unroll
    for (int n = 0; n < 4; ++n) {
        const int gn = n0 + wn * 64 + n * 16 + lr;
        const float bv = bias[gn];
#pragma unroll
        for (int m = 0; m < 4; ++m) {
            const int gmb = m0 + wm * 64 + m * 16 + lg * 4;
            if (MODE == 0) {
                const int sec = gn >> 9, c = gn & 511;
                const int h = c >> 6, d = c & 63;
                const int b = gmb >> 12, t = gmb & 4095;
                if (sec == 2) {
                    // V transposed: VT[bh][d][t], t-contiguous -> one 8B store
                    ushort tmp[4];
#pragma unroll
                    for (int r = 0; r < 4; ++r) tmp[r] = f2b(acc[m][n][r] + bv);
                    *(ushort4*)&VTp[(size_t)(b * 8 + h) * 262144 + (size_t)d * 4096 + t] =
                        *(const ushort4*)tmp;
                } else {
                    const size_t idx0 = ((size_t)(b * 8 + h) * 4096 + t) * 64 + d;
#pragma unroll
                    for (int r = 0; r < 4; ++r) {
                        const float v = acc[m][n][r] + bv;
                        if (sec == 0) Qp[idx0 + (size_t)r * 64] = f2b(v * 0.125f);
                        else          Kp[idx0 + (size_t)r * 64] = f2b(v);
                    }
                }
            } else {
#pragma unroll
                for (int r = 0; r < 4; ++r)
                    outF[(size_t)(gmb + r) * 512 + gn] = acc[m][n][r] + bv;
            }
        }
    }
}

// ---------------- flash attention, 4 waves x 32 q-rows, KVBLK=64, swapped QK^T ----------------
// Q,K: [bh][T][64] bf16 (Q pre-scaled by 0.125), VT: [bh][64][T] bf16
// out: bf16 [B][T][512]
__global__ __launch_bounds__(256) void k_attn(const ushort* __restrict__ Q,
                                              const ushort* __restrict__ K,
                                              const ushort* __restrict__ VT,
                                              ushort* __restrict__ Outp) {
    __shared__ __align__(16) ushort sm[16384];   // 2 bufs x (K 8KB + V 8KB)
    const int tid = threadIdx.x;
    const int lane = tid & 63, w = tid >> 6;
    const int lg2 = lane >> 5, l31 = lane & 31, l7 = lane & 7;
    const int qt = 31 - (int)blockIdx.y;          // heavy tiles dispatch first (ids 0..15)
    const int bh = blockIdx.x;
    const int q0 = qt * 128;
    const int qbase = q0 + w * 32;
    const size_t base = (size_t)bh * 4096 * 64;
    const ushort* Kb = K + base;
    const ushort* Vb = VT + base;                 // [64][4096]
    const ushort* Qb = Q + base;

    // Q fragments: B-operand of 32x32x16 (col = lane&31 -> q row, k = (lane>>5)*8+e)
    bf16x8 qf[4];
#pragma unroll
    for (int ks = 0; ks < 4; ++ks)
        qf[ks] = *(const bf16x8*)&Qb[(size_t)(qbase + l31) * 64 + ks * 16 + lg2 * 8];
    // drain so the in-loop vmcnt counting is exact
    asm volatile("s_waitcnt vmcnt(0)" ::: "memory");
    __builtin_amdgcn_sched_barrier(0);

    const int srow = lane >> 3;                   // 0..7
    const int sslot = l7 ^ srow;                  // pre-swizzled global slot (rule 21)

    auto STAGE = [&](int buf, int kv0) {          // 4 glds16 per thread
#pragma unroll
        for (int j = 0; j < 2; ++j) {
            const int r = j * 32 + w * 8 + srow;  // kv row
            glds16(Kb + (size_t)(kv0 + r) * 64 + sslot * 8,
                   (char*)sm + buf * 16384 + j * 4096 + w * 1024);
        }
#pragma unroll
        for (int j = 0; j < 2; ++j) {
            const int r = j * 32 + w * 8 + srow;  // d row
            glds16(Vb + (size_t)r * 4096 + kv0 + sslot * 8,
                   (char*)sm + buf * 16384 + 8192 + j * 4096 + w * 1024);
        }
    };

    f32x16 oacc0 = z16(), oacc1 = z16();          // O^T: col=q (lane&31), rows=d pattern
    float mrun = -1e30f, lrun = 0.f;
    const int NT = 2 * qt + 2;

    STAGE(0, 0);                                  // 4 outstanding
    for (int it = 0; it < NT; ++it) {
        const int kv0 = it * 64;
        const int bsel = it & 1;
        if (it + 1 < NT) {
            STAGE(bsel ^ 1, kv0 + 64);            // 8 outstanding
            asm volatile("s_waitcnt vmcnt(4)" ::: "memory");   // prev tile landed; next stays in flight
        } else {
            asm volatile("s_waitcnt vmcnt(0)" ::: "memory");
        }
        __builtin_amdgcn_sched_barrier(0);
        __builtin_amdgcn_s_barrier();             // all waves: buf[bsel] resident
        asm volatile("" ::: "memory");

        const bool live0 = (kv0 <= qbase + 31);
        const bool live1 = (kv0 + 32 <= qbase + 31);
        if (live0) {
            const ushort* bK = sm + bsel * 8192;
            const ushort* bV = bK + 4096;

            // S^T = K x Q^T : col = q = lane&31, kv rows reg-distributed
            f32x16 st0 = z16(), st1 = z16();
            __builtin_amdgcn_s_setprio(1);
#pragma unroll
            for (int ks = 0; ks < 4; ++ks) {
                bf16x8 kf = *(const bf16x8*)&bK[l31 * 64 + (((2 * ks + lg2) ^ l7)) * 8];
                st0 = __builtin_amdgcn_mfma_f32_32x32x16_bf16(kf, qf[ks], st0, 0, 0, 0);
            }
            if (live1) {
#pragma unroll
                for (int ks = 0; ks < 4; ++ks) {
                    bf16x8 kf = *(const bf16x8*)&bK[(32 + l31) * 64 + (((2 * ks + lg2) ^ l7)) * 8];
                    st1 = __builtin_amdgcn_mfma_f32_32x32x16_bf16(kf, qf[ks], st1, 0, 0, 0);
                }
            }
            __builtin_amdgcn_s_setprio(0);
            if (kv0 == qbase) {                   // diagonal tile 0
#pragma unroll
                for (int r = 0; r < 16; ++r) {
                    const int rowk = (r & 3) + 8 * (r >> 2) + 4 * lg2;
                    if (rowk > l31) st0[r] = -1e30f;
                }
            }
            if (live1 && kv0 + 32 == qbase) {     // diagonal tile 1
#pragma unroll
                for (int r = 0; r < 16; ++r) {
                    const int rowk = (r & 3) + 8 * (r >> 2) + 4 * lg2;
                    if (rowk > l31) st1[r] = -1e30f;
                }
            }

            // in-lane row max (4 chains), then cross-half via shfl
            float m0 = -1e30f, m1 = -1e30f, m2 = -1e30f, m3 = -1e30f;
#pragma unroll
            for (int r = 0; r < 16; r += 4) {
                m0 = fmaxf(m0, st0[r]);     m1 = fmaxf(m1, st0[r + 1]);
                m2 = fmaxf(m2, st0[r + 2]); m3 = fmaxf(m3, st0[r + 3]);
            }
            if (live1) {
#pragma unroll
                for (int r = 0; r < 16; r += 4) {
                    m0 = fmaxf(m0, st1[r]);     m1 = fmaxf(m1, st1[r + 1]);
                    m2 = fmaxf(m2, st1[r + 2]); m3 = fmaxf(m3, st1[r + 3]);
                }
            }
            float tmax = fmaxf(fmaxf(m0, m1), fmaxf(m2, m3));
            tmax = fmaxf(tmax, __shfl_xor(tmax, 32));

            const float mnew = fmaxf(mrun, tmax);
            const float al = __builtin_amdgcn_exp2f((mrun - mnew) * LOG2E);
            const float ml2 = mnew * LOG2E;
            mrun = mnew;

            float s0 = 0.f, s1 = 0.f, s2 = 0.f, s3 = 0.f;
#pragma unroll
            for (int r = 0; r < 16; r += 4) {
                st0[r]     = __builtin_amdgcn_exp2f(fmaf(st0[r],     LOG2E, -ml2)); s0 += st0[r];
                st0[r + 1] = __builtin_amdgcn_exp2f(fmaf(st0[r + 1], LOG2E, -ml2)); s1 += st0[r + 1];
                st0[r + 2] = __builtin_amdgcn_exp2f(fmaf(st0[r + 2], LOG2E, -ml2)); s2 += st0[r + 2];
                st0[r + 3] = __builtin_amdgcn_exp2f(fmaf(st0[r + 3], LOG2E, -ml2)); s3 += st0[r + 3];
            }
            if (live1) {
#pragma unroll
                for (int r = 0; r < 16; r += 4) {
                    st1[r]     = __builtin_amdgcn_exp2f(fmaf(st1[r],     LOG2E, -ml2)); s0 += st1[r];
                    st1[r + 1] = __builtin_amdgcn_exp2f(fmaf(st1[r + 1], LOG2E, -ml2)); s1 += st1[r + 1];
                    st1[r + 2] = __builtin_amdgcn_exp2f(fmaf(st1[r + 2], LOG2E, -ml2)); s2 += st1[r + 2];
                    st1[r + 3] = __builtin_amdgcn_exp2f(fmaf(st1[r + 3], LOG2E, -ml2)); s3 += st1[r + 3];
                }
            }
            float psum = (s0 + s1) + (s2 + s3);
            psum += __shfl_xor(psum, 32);
            lrun = lrun * al + psum;
#pragma unroll
            for (int r = 0; r < 16; ++r) { oacc0[r] *= al; oacc1[r] *= al; }

            // P -> bf16 B-frag via cvt_pk + cross-half shfl, then PV (O^T = V^T x P^T)
#pragma unroll
            for (int stp = 0; stp < 4; ++stp) {
                if (stp >= 2 && !live1) continue;
                const int h = stp & 1;
                uint32_t a0, a1, b0, b1;
                if (stp < 2) {
                    a0 = cvt_pk_bf16(st0[h * 8 + 0], st0[h * 8 + 1]);
                    a1 = cvt_pk_bf16(st0[h * 8 + 2], st0[h * 8 + 3]);
                    b0 = cvt_pk_bf16(st0[h * 8 + 4], st0[h * 8 + 5]);
                    b1 = cvt_pk_bf16(st0[h * 8 + 6], st0[h * 8 + 7]);
                } else {
                    a0 = cvt_pk_bf16(st1[h * 8 + 0], st1[h * 8 + 1]);
                    a1 = cvt_pk_bf16(st1[h * 8 + 2], st1[h * 8 + 3]);
                    b0 = cvt_pk_bf16(st1[h * 8 + 4], st1[h * 8 + 5]);
                    b1 = cvt_pk_bf16(st1[h * 8 + 6], st1[h * 8 + 7]);
                }
                const uint32_t pa0 = (uint32_t)__shfl_xor((int)a0, 32);
                const uint32_t pa1 = (uint32_t)__shfl_xor((int)a1, 32);
                const uint32_t pb0 = (uint32_t)__shfl_xor((int)b0, 32);
                const uint32_t pb1 = (uint32_t)__shfl_xor((int)b1, 32);
                union { uint32_t u[4]; bf16x8 v; } pk;
                pk.u[0] = lg2 ? pb0 : a0;
                pk.u[1] = lg2 ? pb1 : a1;
                pk.u[2] = lg2 ? b0 : pa0;
                pk.u[3] = lg2 ? b1 : pa1;
                const int vs = (((2 * stp + lg2) ^ l7)) * 8;
                bf16x8 vf0 = *(const bf16x8*)&bV[l31 * 64 + vs];
                bf16x8 vf1 = *(const bf16x8*)&bV[(32 + l31) * 64 + vs];
                __builtin_amdgcn_s_setprio(1);
                oacc0 = __builtin_amdgcn_mfma_f32_32x32x16_bf16(vf0, pk.v, oacc0, 0, 0, 0);
                oacc1 = __builtin_amdgcn_mfma_f32_32x32x16_bf16(vf1, pk.v, oacc1, 0, 0, 0);
                __builtin_amdgcn_s_setprio(0);
            }
        }
        asm volatile("" ::: "memory");
        __builtin_amdgcn_s_barrier();             // all reads of buf[bsel] done
    }

    // epilogue: O^T -> LDS transpose (per-warp region) -> coalesced global store
    const float inv = 1.0f / lrun;
    ushort* ep = sm + w * 2304;                   // [32 q][72] ushort
#pragma unroll
    for (int r = 0; r < 16; ++r) {
        const int dd = (r & 3) + 8 * (r >> 2) + 4 * lg2;
        ep[l31 * 72 + dd]      = f2b(oacc0[r] * inv);
        ep[l31 * 72 + 32 + dd] = f2b(oacc1[r] * inv);
    }
    asm volatile("s_waitcnt lgkmcnt(0)" ::: "memory");
    __builtin_amdgcn_sched_barrier(0);
    const int qq = lane >> 1, half = lane & 1;
    const int bb = bh >> 3, hh = bh & 7;
    const int tg = q0 + w * 32 + qq;
    ushort* op = Outp + ((size_t)(bb * 4096 + tg) * 512 + hh * 64 + half * 32);
#pragma unroll
    for (int j = 0; j < 4; ++j) {
        uint4 v = *(const uint4*)&ep[qq * 72 + half * 32 + j * 8];
        *(uint4*)&op[j * 8] = v;
    }
}

extern "C" void kernel_launch(void* const* d_in, const int* in_sizes, int n_in,
                              void* d_out, int out_size, void* d_ws, size_t ws_size,
                              hipStream_t stream) {
    const float* x    = (const float*)d_in[0];
    const float* Wqkv = (const float*)d_in[1];
    const float* bqkv = (const float*)d_in[2];
    const float* Wout = (const float*)d_in[3];
    const float* bout = (const float*)d_in[4];
    float* out = (float*)d_out;

    char* ws = (char*)d_ws;
    ushort* xb    = (ushort*)(ws);                 // 8 MB (x bf16, later attn out)
    ushort* wqkvT = (ushort*)(ws + 8388608);       // 1.5 MB
    ushort* woutT = (ushort*)(ws + 9961472);       // 0.5 MB
    ushort* Qp    = (ushort*)(ws + 10485760);      // 8 MB
    ushort* Kp    = (ushort*)(ws + 18874368);      // 8 MB
    ushort* VTp   = (ushort*)(ws + 27262976);      // 8 MB  (total 36 MB)

    k_convert<<<2048, 256, 0, stream>>>(x, xb, 524288);
    k_transpose_w<<<dim3(48, 16), dim3(32, 8), 0, stream>>>(Wqkv, wqkvT, 512, 1536);
    k_transpose_w<<<dim3(16, 16), dim3(32, 8), 0, stream>>>(Wout, woutT, 512, 512);
    k_gemm<0><<<dim3(64, 12), 256, 0, stream>>>(xb, wqkvT, bqkv, nullptr, Qp, Kp, VTp, 512);
    k_attn<<<dim3(16, 32), 256, 0, stream>>>(Qp, Kp, VTp, xb);
    k_gemm<1><<<dim3(64, 4), 256, 0, stream>>>(xb, woutT, bout, out, nullptr, nullptr, nullptr, 512);
}

// Round 5
// 137.782 us; speedup vs baseline: 2.9660x; 1.1891x over previous
//
#include <hip/hip_runtime.h>
#include <hip/hip_bf16.h>
#include <cstdint>
#include <cstddef>

typedef __attribute__((ext_vector_type(8))) __bf16 bf16x8;
typedef __attribute__((ext_vector_type(4))) float f32x4;
typedef __attribute__((ext_vector_type(16))) float f32x16;

#define LOG2E 1.4426950408889634f

__device__ __forceinline__ ushort f2b(float x) {
    union { float f; uint32_t u; } v; v.f = x;
    uint32_t r = v.u + 0x7FFFu + ((v.u >> 16) & 1u);   // RNE
    return (ushort)(r >> 16);
}

__device__ __forceinline__ void glds16(const void* g, void* l) {
    __builtin_amdgcn_global_load_lds(
        (const __attribute__((address_space(1))) void*)g,
        (__attribute__((address_space(3))) void*)l, 16, 0, 0);
}

__device__ __forceinline__ uint32_t cvt_pk_bf16(float lo, float hi) {
    uint32_t r;
    asm("v_cvt_pk_bf16_f32 %0, %1, %2" : "=v"(r) : "v"(lo), "v"(hi));
    return r;
}

__device__ __forceinline__ f32x16 z16() {
    f32x16 v;
#pragma unroll
    for (int i = 0; i < 16; ++i) v[i] = 0.f;
    return v;
}

// ---------------- convert f32 -> bf16, 8 elems/thread ----------------
__global__ __launch_bounds__(256) void k_convert(const float* __restrict__ in,
                                                 ushort* __restrict__ out, int n8) {
    int i = blockIdx.x * 256 + threadIdx.x;
    if (i >= n8) return;
    const float4* p = (const float4*)in + (size_t)i * 2;
    float4 a = p[0], b = p[1];
    ushort o[8] = { f2b(a.x), f2b(a.y), f2b(a.z), f2b(a.w),
                    f2b(b.x), f2b(b.y), f2b(b.z), f2b(b.w) };
    *(uint4*)(out + (size_t)i * 8) = *(const uint4*)o;
}

// ------------- transpose-convert: in f32 [R][C] -> out bf16 [C][R] -------------
__global__ __launch_bounds__(256) void k_transpose_w(const float* __restrict__ in,
                                                     ushort* __restrict__ out,
                                                     int R, int C) {
    __shared__ float tile[32][33];
    int c0 = blockIdx.x * 32, r0 = blockIdx.y * 32;
    int tx = threadIdx.x, ty = threadIdx.y;   // (32,8)
#pragma unroll
    for (int i = 0; i < 32; i += 8)
        tile[ty + i][tx] = in[(size_t)(r0 + ty + i) * C + c0 + tx];
    __syncthreads();
#pragma unroll
    for (int i = 0; i < 32; i += 8)
        out[(size_t)(c0 + ty + i) * R + r0 + tx] = f2b(tile[tx][ty + i]);
}

// ---------------- bf16 GEMM, A [M][K] x BT [N][K] (=B^T), 128x128 tile ----------------
// MODE 0: epilogue scatters Q(*0.125)/K bf16 to [B*H][T][D] and V transposed to
//         VT [B*H][D][T] (8B t-contiguous stores), bias=bqkv
// MODE 1: epilogue writes f32 out[M][512] + bias
template <int MODE>
__global__ __launch_bounds__(256) void k_gemm(const ushort* __restrict__ A,
                                              const ushort* __restrict__ BT,
                                              const float* __restrict__ bias,
                                              float* __restrict__ outF,
                                              ushort* __restrict__ Qp,
                                              ushort* __restrict__ Kp,
                                              ushort* __restrict__ VTp,
                                              int K) {
    __shared__ __align__(16) ushort lA[128 * 32];
    __shared__ __align__(16) ushort lB[128 * 32];
    const int tid = threadIdx.x;
    const int lane = tid & 63, lr = lane & 15, lg = lane >> 4;
    const int wid = tid >> 6, wm = wid >> 1, wn = wid & 1;
    const int m0 = blockIdx.x * 128, n0 = blockIdx.y * 128;

    const ushort* ga = A + (size_t)(m0 + (tid >> 2)) * K + (tid & 3) * 8;
    const ushort* gb = BT + (size_t)(n0 + (tid >> 2)) * K + (tid & 3) * 8;
    const size_t rstep = (size_t)64 * K;

    f32x4 zero = {0.f, 0.f, 0.f, 0.f};
    f32x4 acc[4][4];
#pragma unroll
    for (int i = 0; i < 4; ++i)
#pragma unroll
        for (int j = 0; j < 4; ++j) acc[i][j] = zero;

    for (int k0 = 0; k0 < K; k0 += 32) {
        glds16(ga + k0,         &lA[tid * 8]);
        glds16(ga + k0 + rstep, &lA[2048 + tid * 8]);
        glds16(gb + k0,         &lB[tid * 8]);
        glds16(gb + k0 + rstep, &lB[2048 + tid * 8]);
        __syncthreads();
        bf16x8 af[4], bfr[4];
#pragma unroll
        for (int m = 0; m < 4; ++m)
            af[m] = *(const bf16x8*)&lA[(wm * 64 + m * 16 + lr) * 32 + lg * 8];
#pragma unroll
        for (int n = 0; n < 4; ++n)
            bfr[n] = *(const bf16x8*)&lB[(wn * 64 + n * 16 + lr) * 32 + lg * 8];
#pragma unroll
        for (int m = 0; m < 4; ++m)
#pragma unroll
            for (int n = 0; n < 4; ++n)
                acc[m][n] = __builtin_amdgcn_mfma_f32_16x16x32_bf16(af[m], bfr[n], acc[m][n], 0, 0, 0);
        __syncthreads();
    }

#pragma unroll
    for (int n = 0; n < 4; ++n) {
        const int gn = n0 + wn * 64 + n * 16 + lr;
        const float bv = bias[gn];
#pragma unroll
        for (int m = 0; m < 4; ++m) {
            const int gmb = m0 + wm * 64 + m * 16 + lg * 4;
            if (MODE == 0) {
                const int sec = gn >> 9, c = gn & 511;
                const int h = c >> 6, d = c & 63;
                const int b = gmb >> 12, t = gmb & 4095;
                if (sec == 2) {
                    ushort tmp[4];
#pragma unroll
                    for (int r = 0; r < 4; ++r) tmp[r] = f2b(acc[m][n][r] + bv);
                    *(ushort4*)&VTp[(size_t)(b * 8 + h) * 262144 + (size_t)d * 4096 + t] =
                        *(const ushort4*)tmp;
                } else {
                    const size_t idx0 = ((size_t)(b * 8 + h) * 4096 + t) * 64 + d;
#pragma unroll
                    for (int r = 0; r < 4; ++r) {
                        const float v = acc[m][n][r] + bv;
                        if (sec == 0) Qp[idx0 + (size_t)r * 64] = f2b(v * 0.125f);
                        else          Kp[idx0 + (size_t)r * 64] = f2b(v);
                    }
                }
            } else {
#pragma unroll
                for (int r = 0; r < 4; ++r)
                    outF[(size_t)(gmb + r) * 512 + gn] = acc[m][n][r] + bv;
            }
        }
    }
}

// ---------------- attention stream: one q-tile (128 rows), KV tiles [kv_lo,kv_hi) --------
// MODE 0: divide by l, transpose via LDS, write final bf16 to Outp
// MODE 1: write partial O^T f32 [64][128] + m,l to pO/pML
template <int MODE>
__device__ __forceinline__ void attn_run(const ushort* __restrict__ Qb,
                                         const ushort* __restrict__ Kb,
                                         const ushort* __restrict__ Vb,
                                         ushort* sm, int qt, int kv_lo, int kv_hi,
                                         int lane, int w,
                                         ushort* __restrict__ Outp, int bh,
                                         float* __restrict__ pO,
                                         float* __restrict__ pML) {
    const int lg2 = lane >> 5, l31 = lane & 31, l7 = lane & 7;
    const int q0 = qt * 128;
    const int qbase = q0 + w * 32;

    // Q fragments: B-operand of 32x32x16 (col = lane&31 -> q row, k = (lane>>5)*8+e)
    bf16x8 qf[4];
#pragma unroll
    for (int ks = 0; ks < 4; ++ks)
        qf[ks] = *(const bf16x8*)&Qb[(size_t)(qbase + l31) * 64 + ks * 16 + lg2 * 8];
    // drain so the in-loop vmcnt counting is exact (also drains any prior stores)
    asm volatile("s_waitcnt vmcnt(0)" ::: "memory");
    __builtin_amdgcn_sched_barrier(0);

    const int srow = lane >> 3;                   // 0..7
    const int sslot = l7 ^ srow;                  // pre-swizzled global slot (rule 21)

    auto STAGE = [&](int buf, int kv0) {          // 4 glds16 per thread
#pragma unroll
        for (int j = 0; j < 2; ++j) {
            const int r = j * 32 + w * 8 + srow;  // kv row
            glds16(Kb + (size_t)(kv0 + r) * 64 + sslot * 8,
                   (char*)sm + buf * 16384 + j * 4096 + w * 1024);
        }
#pragma unroll
        for (int j = 0; j < 2; ++j) {
            const int r = j * 32 + w * 8 + srow;  // d row
            glds16(Vb + (size_t)r * 4096 + kv0 + sslot * 8,
                   (char*)sm + buf * 16384 + 8192 + j * 4096 + w * 1024);
        }
    };

    f32x16 oacc0 = z16(), oacc1 = z16();          // O^T: col=q (lane&31), rows=d pattern
    float mrun = -1e30f, lrun = 0.f;

    STAGE(0, kv_lo * 64);                         // 4 outstanding
    for (int it = kv_lo; it < kv_hi; ++it) {
        const int kv0 = it * 64;
        const int bsel = (it - kv_lo) & 1;
        if (it + 1 < kv_hi) {
            STAGE(bsel ^ 1, kv0 + 64);            // 8 outstanding
            asm volatile("s_waitcnt vmcnt(4)" ::: "memory");
        } else {
            asm volatile("s_waitcnt vmcnt(0)" ::: "memory");
        }
        __builtin_amdgcn_sched_barrier(0);
        __builtin_amdgcn_s_barrier();             // all waves: buf[bsel] resident
        asm volatile("" ::: "memory");

        const bool live0 = (kv0 <= qbase + 31);
        const bool live1 = (kv0 + 32 <= qbase + 31);
        if (live0) {
            const ushort* bK = sm + bsel * 8192;
            const ushort* bV = bK + 4096;

            // S^T = K x Q^T : col = q = lane&31, kv rows reg-distributed
            f32x16 st0 = z16(), st1 = z16();
            __builtin_amdgcn_s_setprio(1);
#pragma unroll
            for (int ks = 0; ks < 4; ++ks) {
                bf16x8 kf = *(const bf16x8*)&bK[l31 * 64 + (((2 * ks + lg2) ^ l7)) * 8];
                st0 = __builtin_amdgcn_mfma_f32_32x32x16_bf16(kf, qf[ks], st0, 0, 0, 0);
            }
            if (live1) {
#pragma unroll
                for (int ks = 0; ks < 4; ++ks) {
                    bf16x8 kf = *(const bf16x8*)&bK[(32 + l31) * 64 + (((2 * ks + lg2) ^ l7)) * 8];
                    st1 = __builtin_amdgcn_mfma_f32_32x32x16_bf16(kf, qf[ks], st1, 0, 0, 0);
                }
            }
            __builtin_amdgcn_s_setprio(0);
            if (kv0 == qbase) {                   // diagonal tile 0
#pragma unroll
                for (int r = 0; r < 16; ++r) {
                    const int rowk = (r & 3) + 8 * (r >> 2) + 4 * lg2;
                    if (rowk > l31) st0[r] = -1e30f;
                }
            }
            if (live1 && kv0 + 32 == qbase) {     // diagonal tile 1
#pragma unroll
                for (int r = 0; r < 16; ++r) {
                    const int rowk = (r & 3) + 8 * (r >> 2) + 4 * lg2;
                    if (rowk > l31) st1[r] = -1e30f;
                }
            }

            // in-lane row max (4 chains), then cross-half via shfl
            float m0 = -1e30f, m1 = -1e30f, m2 = -1e30f, m3 = -1e30f;
#pragma unroll
            for (int r = 0; r < 16; r += 4) {
                m0 = fmaxf(m0, st0[r]);     m1 = fmaxf(m1, st0[r + 1]);
                m2 = fmaxf(m2, st0[r + 2]); m3 = fmaxf(m3, st0[r + 3]);
            }
            if (live1) {
#pragma unroll
                for (int r = 0; r < 16; r += 4) {
                    m0 = fmaxf(m0, st1[r]);     m1 = fmaxf(m1, st1[r + 1]);
                    m2 = fmaxf(m2, st1[r + 2]); m3 = fmaxf(m3, st1[r + 3]);
                }
            }
            float tmax = fmaxf(fmaxf(m0, m1), fmaxf(m2, m3));
            tmax = fmaxf(tmax, __shfl_xor(tmax, 32));

            // exact defer-max: only rescale when some lane's max grew
            if (__any((int)(tmax > mrun))) {
                const float mnew = fmaxf(mrun, tmax);
                const float al = __builtin_amdgcn_exp2f((mrun - mnew) * LOG2E);
                mrun = mnew;
                lrun *= al;
#pragma unroll
                for (int r = 0; r < 16; ++r) { oacc0[r] *= al; oacc1[r] *= al; }
            }
            const float ml2 = mrun * LOG2E;

            float s0 = 0.f, s1 = 0.f, s2 = 0.f, s3 = 0.f;
#pragma unroll
            for (int r = 0; r < 16; r += 4) {
                st0[r]     = __builtin_amdgcn_exp2f(fmaf(st0[r],     LOG2E, -ml2)); s0 += st0[r];
                st0[r + 1] = __builtin_amdgcn_exp2f(fmaf(st0[r + 1], LOG2E, -ml2)); s1 += st0[r + 1];
                st0[r + 2] = __builtin_amdgcn_exp2f(fmaf(st0[r + 2], LOG2E, -ml2)); s2 += st0[r + 2];
                st0[r + 3] = __builtin_amdgcn_exp2f(fmaf(st0[r + 3], LOG2E, -ml2)); s3 += st0[r + 3];
            }
            if (live1) {
#pragma unroll
                for (int r = 0; r < 16; r += 4) {
                    st1[r]     = __builtin_amdgcn_exp2f(fmaf(st1[r],     LOG2E, -ml2)); s0 += st1[r];
                    st1[r + 1] = __builtin_amdgcn_exp2f(fmaf(st1[r + 1], LOG2E, -ml2)); s1 += st1[r + 1];
                    st1[r + 2] = __builtin_amdgcn_exp2f(fmaf(st1[r + 2], LOG2E, -ml2)); s2 += st1[r + 2];
                    st1[r + 3] = __builtin_amdgcn_exp2f(fmaf(st1[r + 3], LOG2E, -ml2)); s3 += st1[r + 3];
                }
            }
            float psum = (s0 + s1) + (s2 + s3);
            psum += __shfl_xor(psum, 32);
            lrun += psum;

            // P -> bf16 B-frag via cvt_pk + cross-half shfl, then PV (O^T = V^T x P^T)
#pragma unroll
            for (int stp = 0; stp < 4; ++stp) {
                if (stp >= 2 && !live1) continue;
                const int h = stp & 1;
                uint32_t a0, a1, b0, b1;
                if (stp < 2) {
                    a0 = cvt_pk_bf16(st0[h * 8 + 0], st0[h * 8 + 1]);
                    a1 = cvt_pk_bf16(st0[h * 8 + 2], st0[h * 8 + 3]);
                    b0 = cvt_pk_bf16(st0[h * 8 + 4], st0[h * 8 + 5]);
                    b1 = cvt_pk_bf16(st0[h * 8 + 6], st0[h * 8 + 7]);
                } else {
                    a0 = cvt_pk_bf16(st1[h * 8 + 0], st1[h * 8 + 1]);
                    a1 = cvt_pk_bf16(st1[h * 8 + 2], st1[h * 8 + 3]);
                    b0 = cvt_pk_bf16(st1[h * 8 + 4], st1[h * 8 + 5]);
                    b1 = cvt_pk_bf16(st1[h * 8 + 6], st1[h * 8 + 7]);
                }
                const uint32_t pa0 = (uint32_t)__shfl_xor((int)a0, 32);
                const uint32_t pa1 = (uint32_t)__shfl_xor((int)a1, 32);
                const uint32_t pb0 = (uint32_t)__shfl_xor((int)b0, 32);
                const uint32_t pb1 = (uint32_t)__shfl_xor((int)b1, 32);
                union { uint32_t u[4]; bf16x8 v; } pk;
                pk.u[0] = lg2 ? pb0 : a0;
                pk.u[1] = lg2 ? pb1 : a1;
                pk.u[2] = lg2 ? b0 : pa0;
                pk.u[3] = lg2 ? b1 : pa1;
                const int vs = (((2 * stp + lg2) ^ l7)) * 8;
                bf16x8 vf0 = *(const bf16x8*)&bV[l31 * 64 + vs];
                bf16x8 vf1 = *(const bf16x8*)&bV[(32 + l31) * 64 + vs];
                __builtin_amdgcn_s_setprio(1);
                oacc0 = __builtin_amdgcn_mfma_f32_32x32x16_bf16(vf0, pk.v, oacc0, 0, 0, 0);
                oacc1 = __builtin_amdgcn_mfma_f32_32x32x16_bf16(vf1, pk.v, oacc1, 0, 0, 0);
                __builtin_amdgcn_s_setprio(0);
            }
        }
        asm volatile("" ::: "memory");
        __builtin_amdgcn_s_barrier();             // all reads of buf[bsel] done
    }

    if (MODE == 0) {
        // epilogue: O^T -> LDS transpose (per-warp region) -> coalesced global store
        const float inv = 1.0f / lrun;
        ushort* ep = sm + w * 2304;               // [32 q][72] ushort
#pragma unroll
        for (int r = 0; r < 16; ++r) {
            const int dd = (r & 3) + 8 * (r >> 2) + 4 * lg2;
            ep[l31 * 72 + dd]      = f2b(oacc0[r] * inv);
            ep[l31 * 72 + 32 + dd] = f2b(oacc1[r] * inv);
        }
        asm volatile("s_waitcnt lgkmcnt(0)" ::: "memory");
        __builtin_amdgcn_sched_barrier(0);
        const int qq = lane >> 1, half = lane & 1;
        const int bb = bh >> 3, hh = bh & 7;
        const int tg = q0 + w * 32 + qq;
        ushort* op = Outp + ((size_t)(bb * 4096 + tg) * 512 + hh * 64 + half * 32);
#pragma unroll
        for (int j = 0; j < 4; ++j) {
            uint4 v = *(const uint4*)&ep[qq * 72 + half * 32 + j * 8];
            *(uint4*)&op[j * 8] = v;
        }
    } else {
        // partial: O^T f32 [64][128] (q-contiguous rows), m/l [2][128]
        const int qc = w * 32 + l31;
#pragma unroll
        for (int r = 0; r < 16; ++r) {
            const int dd = (r & 3) + 8 * (r >> 2) + 4 * lg2;
            pO[dd * 128 + qc]        = oacc0[r];
            pO[(dd + 32) * 128 + qc] = oacc1[r];
        }
        if (lg2 == 0) {
            pML[qc]       = mrun;
            pML[128 + qc] = lrun;
        }
    }
}

// fold+split causal attention: pair (p, 31-p), half A = heavy KV [0,33),
// half B = heavy KV [33, 64-2p) partial + light full (final)
__global__ __launch_bounds__(256) void k_attn(const ushort* __restrict__ Q,
                                              const ushort* __restrict__ K,
                                              const ushort* __restrict__ VT,
                                              ushort* __restrict__ Outp,
                                              float* __restrict__ pO,
                                              float* __restrict__ pML) {
    __shared__ __align__(16) ushort sm[16384];   // 2 bufs x (K 8KB + V 8KB)
    const int tid = threadIdx.x;
    const int lane = tid & 63, w = tid >> 6;
    const int bh = blockIdx.x;
    const int s = blockIdx.y;                     // 0..31
    const int p = s >> 1, half = s & 1;
    const int qtH = 31 - p;
    const size_t base = (size_t)bh * 4096 * 64;
    const ushort* Qb = Q + base;
    const ushort* Kb = K + base;
    const ushort* Vb = VT + base;                 // [64][4096]

    float* pOA  = pO  + ((size_t)(bh * 16 + p) * 2) * 8192;
    float* pMLA = pML + ((size_t)(bh * 16 + p) * 2) * 256;

    if (half == 0) {
        attn_run<1>(Qb, Kb, Vb, sm, qtH, 0, 33, lane, w, nullptr, bh, pOA, pMLA);
    } else {
        attn_run<1>(Qb, Kb, Vb, sm, qtH, 33, 64 - 2 * p, lane, w, nullptr, bh,
                    pOA + 8192, pMLA + 256);
        attn_run<0>(Qb, Kb, Vb, sm, p, 0, 2 * p + 2, lane, w, Outp, bh,
                    nullptr, nullptr);
    }
}

// merge the two partials for each heavy tile, write final bf16
__global__ __launch_bounds__(256) void k_merge(const float* __restrict__ pO,
                                               const float* __restrict__ pML,
                                               ushort* __restrict__ Outp) {
    const int bh = blockIdx.x;                    // 16
    const int p = blockIdx.y;                     // 16
    const int qtH = 31 - p;
    const int tid = threadIdx.x;
    const int q = tid >> 1, dh = (tid & 1) * 32;
    const size_t baseA = ((size_t)(bh * 16 + p) * 2);
    const float* OA = pO + baseA * 8192;
    const float* OB = OA + 8192;
    const float* MA = pML + baseA * 256;
    const float* MB = MA + 256;
    const float mA = MA[q], lA = MA[128 + q];
    const float mB = MB[q], lB = MB[128 + q];
    const float m = fmaxf(mA, mB);
    const float sA = __builtin_amdgcn_exp2f((mA - m) * LOG2E);
    const float sB = __builtin_amdgcn_exp2f((mB - m) * LOG2E);
    const float inv = 1.0f / (lA * sA + lB * sB);
    ushort outv[32];
#pragma unroll
    for (int j = 0; j < 32; ++j) {
        const float o = (OA[(dh + j) * 128 + q] * sA + OB[(dh + j) * 128 + q] * sB) * inv;
        outv[j] = f2b(o);
    }
    const int b = bh >> 3, h = bh & 7;
    const int t = qtH * 128 + q;
    ushort* op = Outp + ((size_t)(b * 4096 + t) * 512 + h * 64 + dh);
#pragma unroll
    for (int j = 0; j < 4; ++j) *(uint4*)&op[j * 8] = *(const uint4*)&outv[j * 8];
}

extern "C" void kernel_launch(void* const* d_in, const int* in_sizes, int n_in,
                              void* d_out, int out_size, void* d_ws, size_t ws_size,
                              hipStream_t stream) {
    const float* x    = (const float*)d_in[0];
    const float* Wqkv = (const float*)d_in[1];
    const float* bqkv = (const float*)d_in[2];
    const float* Wout = (const float*)d_in[3];
    const float* bout = (const float*)d_in[4];
    float* out = (float*)d_out;

    char* ws = (char*)d_ws;
    ushort* xb    = (ushort*)(ws);                 // 8 MB (x bf16, later attn out)
    ushort* wqkvT = (ushort*)(ws + 8388608);       // 1.5 MB
    ushort* woutT = (ushort*)(ws + 9961472);       // 0.5 MB
    ushort* Qp    = (ushort*)(ws + 10485760);      // 8 MB
    ushort* Kp    = (ushort*)(ws + 18874368);      // 8 MB
    ushort* VTp   = (ushort*)(ws + 27262976);      // 8 MB
    float*  pO    = (float*)(ws + 35651584);       // 16 MB
    float*  pML   = (float*)(ws + 52428800);       // 0.5 MB (total ~50.5 MB)

    k_convert<<<2048, 256, 0, stream>>>(x, xb, 524288);
    k_transpose_w<<<dim3(48, 16), dim3(32, 8), 0, stream>>>(Wqkv, wqkvT, 512, 1536);
    k_transpose_w<<<dim3(16, 16), dim3(32, 8), 0, stream>>>(Wout, woutT, 512, 512);
    k_gemm<0><<<dim3(64, 12), 256, 0, stream>>>(xb, wqkvT, bqkv, nullptr, Qp, Kp, VTp, 512);
    k_attn<<<dim3(16, 32), 256, 0, stream>>>(Qp, Kp, VTp, xb, pO, pML);
    k_merge<<<dim3(16, 16), 256, 0, stream>>>(pO, pML, xb);
    k_gemm<1><<<dim3(64, 4), 256, 0, stream>>>(xb, woutT, bout, out, nullptr, nullptr, nullptr, 512);
}